// Round 10
// baseline (1312.157 us; speedup 1.0000x reference)
//
#include <hip/hip_runtime.h>
#include <hip/hip_fp16.h>

#define NN     100000
#define NE     1600000
#define FEAT   128
#define HID    64
#define OUTD   40
#define BSH    6                          // bucket = dst >> 6 (64 nodes/bucket)
#define BNODES 64
#define NBKT   ((NN + BNODES - 1) / BNODES)   // 1563
#define CAP    1280                       // bucket capacity (mean ~1024, sd ~32)
#define CCHUNK 2048                       // edges per block in pair-scatter

typedef _Float16 half8 __attribute__((ext_vector_type(8)));
typedef float    f32x4 __attribute__((ext_vector_type(4)));

// ---- A. scatter packed (src<<6|dl) into bucket segments ----
__global__ __launch_bounds__(256) void k_pairs(const int* __restrict__ src,
                                               const int* __restrict__ dst,
                                               int* __restrict__ bfill,
                                               int* __restrict__ pairs) {
    __shared__ int bcnt[NBKT];
    __shared__ int gb[NBKT];
    int t = threadIdx.x;
    for (int i = t; i < NBKT; i += 256) bcnt[i] = 0;
    __syncthreads();
    int e0 = blockIdx.x * CCHUNK;
    int pk[8], bb[8], off[8];
    #pragma unroll
    for (int i = 0; i < 8; ++i) {
        int e = e0 + i * 256 + t;
        if (e < NE) {
            int d = dst[e];
            pk[i]  = (src[e] << BSH) | (d & (BNODES - 1));
            bb[i]  = d >> BSH;
            off[i] = atomicAdd(&bcnt[bb[i]], 1);
        } else bb[i] = -1;
    }
    __syncthreads();
    for (int i = t; i < NBKT; i += 256) {
        int c = bcnt[i];
        gb[i] = c ? (i * CAP + atomicAdd(&bfill[i], c)) : 0;
    }
    __syncthreads();
    #pragma unroll
    for (int i = 0; i < 8; ++i)
        if (bb[i] >= 0) pairs[gb[bb[i]] + off[i]] = pk[i];
}

// ---- B. per-bucket degree hist -> global dinv (bucket contains ALL edges to its nodes) ----
__global__ __launch_bounds__(256) void k_degdinv(const int* __restrict__ pairs,
                                                 const int* __restrict__ bfill,
                                                 float* __restrict__ dinv) {
    __shared__ int hist[BNODES];
    int b = blockIdx.x, t = threadIdx.x;
    if (t < BNODES) hist[t] = 0;
    __syncthreads();
    int base = b * CAP, count = bfill[b];
    for (int i = t; i < count; i += 256)
        atomicAdd(&hist[pairs[base + i] & (BNODES - 1)], 1);
    __syncthreads();
    int node = (b << BSH) + t;
    if (t < BNODES && node < NN) dinv[node] = rsqrtf((float)hist[t] + 1.0f);
}

// ---- C. per-bucket counting sort by src stripe (src>>9); fused weights; zero-pad to 32 ----
__global__ __launch_bounds__(256) void k_csr(const int* __restrict__ pairs,
                                             int* __restrict__ bfill,
                                             const float* __restrict__ dinv,
                                             int2* __restrict__ csr) {
    __shared__ int   hist[256];
    __shared__ int   sc[256];
    __shared__ float ldin[BNODES];
    int b = blockIdx.x, t = threadIdx.x;
    hist[t] = 0;
    if (t < BNODES) {
        int node = (b << BSH) + t;
        ldin[t] = dinv[node < NN ? node : NN - 1];
    }
    __syncthreads();
    int base = b * CAP, count = bfill[b];
    for (int i = t; i < count; i += 256)
        atomicAdd(&hist[(pairs[base + i] >> (BSH + 9)) & 255], 1);
    __syncthreads();
    int v = hist[t];
    sc[t] = v;
    __syncthreads();
    for (int off = 1; off < 256; off <<= 1) {
        int u = (t >= off) ? sc[t - off] : 0;
        __syncthreads();
        sc[t] += u;
        __syncthreads();
    }
    hist[t] = sc[t] - v;          // exclusive prefix; becomes slot-grab counter
    __syncthreads();
    for (int i = t; i < count; i += 256) {
        int p  = pairs[base + i];
        int s  = p >> BSH;
        int dl = p & (BNODES - 1);
        int pos = atomicAdd(&hist[(s >> 9) & 255], 1);
        csr[base + pos] = make_int2(p, __float_as_int(dinv[s] * ldin[dl]));
    }
    int padded = (count + 31) & ~31;
    for (int i = count + t; i < padded; i += 256)
        csr[base + i] = make_int2(0, 0);   // w=0 -> contributes nothing
    __syncthreads();
    if (t == 0) bfill[b] = padded;
}

// ---- D. pack W1/W2 into per-lane MFMA B-fragments (f16) ----
__global__ __launch_bounds__(256) void k_wprep(const float* __restrict__ W1,
                                               const float* __restrict__ W2,
                                               _Float16* __restrict__ w1f,
                                               _Float16* __restrict__ w2f) {
    int t = threadIdx.x;
    for (int it = t; it < 16 * 64; it += 256) {   // W1: kk 0..3 x n 0..3
        int f = it >> 6, l = it & 63;
        int kk = f >> 2, n = f & 3;
        int krow = kk * 32 + (l >> 4) * 8;
        int col  = n * 16 + (l & 15);
        #pragma unroll
        for (int i = 0; i < 8; ++i)
            w1f[it * 8 + i] = (_Float16)W1[(krow + i) * HID + col];
    }
    for (int it = t; it < 6 * 64; it += 256) {    // W2: kk 0..1 x n 0..2 (48-col pad)
        int f = it >> 6, l = it & 63;
        int kk = f / 3, n = f - kk * 3;
        int krow = kk * 32 + (l >> 4) * 8;
        int col  = n * 16 + (l & 15);
        #pragma unroll
        for (int i = 0; i < 8; ++i)
            w2f[it * 8 + i] = (col < OUTD) ? (_Float16)W2[(krow + i) * OUTD + col]
                                           : (_Float16)0.f;
    }
}

// ---- E. h1h = f16(x @ W1) via MFMA: wave = 16 rows x 64 cols ----
__global__ __launch_bounds__(256) void k_mgemm1(const float* __restrict__ x,
                                                const _Float16* __restrict__ w1f,
                                                __half* __restrict__ h1h) {
    int wid = (blockIdx.x * 256 + threadIdx.x) >> 6;
    int l = threadIdx.x & 63;
    if (wid >= NN / 16) return;
    half8 bf[4][4];
    #pragma unroll
    for (int kk = 0; kk < 4; ++kk)
        #pragma unroll
        for (int n = 0; n < 4; ++n)
            bf[kk][n] = ((const half8*)w1f)[(kk * 4 + n) * 64 + l];
    f32x4 acc[4] = {};
    int arow = wid * 16 + (l & 15);
    const float* xp = x + (size_t)arow * FEAT + (l >> 4) * 8;
    #pragma unroll
    for (int kk = 0; kk < 4; ++kk) {
        float4 u0 = *(const float4*)(xp + kk * 32);
        float4 u1 = *(const float4*)(xp + kk * 32 + 4);
        half8 af;
        af[0] = (_Float16)u0.x; af[1] = (_Float16)u0.y;
        af[2] = (_Float16)u0.z; af[3] = (_Float16)u0.w;
        af[4] = (_Float16)u1.x; af[5] = (_Float16)u1.y;
        af[6] = (_Float16)u1.z; af[7] = (_Float16)u1.w;
        #pragma unroll
        for (int n = 0; n < 4; ++n)
            acc[n] = __builtin_amdgcn_mfma_f32_16x16x32_f16(af, bf[kk][n], acc[n], 0, 0, 0);
    }
    int orow = wid * 16 + (l >> 4) * 4;
    int ocol = l & 15;
    #pragma unroll
    for (int n = 0; n < 4; ++n)
        #pragma unroll
        for (int r = 0; r < 4; ++r)
            h1h[(size_t)(orow + r) * HID + n * 16 + ocol] = __float2half(acc[n][r]);
}

// ---- F. block-per-bucket edge-parallel aggregation, LDS fp32 accumulator ----
// MODE 0: relu(agg + self + b1) * mask -> outp ; MODE 1: agg + self -> outp
template<int MODE>
__global__ __launch_bounds__(256) void k_bagg(const int2* __restrict__ csr,
                                              const int* __restrict__ bfill,
                                              const float* __restrict__ dinv,
                                              const __half* __restrict__ feat,
                                              const float* __restrict__ b1,
                                              const float* __restrict__ mask,
                                              _Float16* __restrict__ outp) {
    __shared__ float acc[BNODES * HID];   // 16 KB -> 8 blocks/CU
    int t = threadIdx.x, wv = t >> 6, l = t & 63;
    int b = blockIdx.x;
    float4* a4 = (float4*)acc;
    for (int i = t; i < BNODES * HID / 4; i += 256) a4[i] = make_float4(0.f, 0.f, 0.f, 0.f);
    __syncthreads();
    int base = b * CAP;
    int count = bfill[b];                 // padded to multiple of 32 (also of 16)
    for (int j = wv * 4; j < count; j += 16) {
        int2 e0 = csr[base + j + 0];
        int2 e1 = csr[base + j + 1];
        int2 e2 = csr[base + j + 2];
        int2 e3 = csr[base + j + 3];
        float a0 = __half2float(feat[(size_t)(e0.x >> BSH) * HID + l]) * __int_as_float(e0.y);
        float a1 = __half2float(feat[(size_t)(e1.x >> BSH) * HID + l]) * __int_as_float(e1.y);
        float a2 = __half2float(feat[(size_t)(e2.x >> BSH) * HID + l]) * __int_as_float(e2.y);
        float a3 = __half2float(feat[(size_t)(e3.x >> BSH) * HID + l]) * __int_as_float(e3.y);
        atomicAdd(&acc[((e0.x & (BNODES - 1)) << 6) | l], a0);
        atomicAdd(&acc[((e1.x & (BNODES - 1)) << 6) | l], a1);
        atomicAdd(&acc[((e2.x & (BNODES - 1)) << 6) | l], a2);
        atomicAdd(&acc[((e3.x & (BNODES - 1)) << 6) | l], a3);
    }
    __syncthreads();
    for (int n = wv; n < BNODES; n += 4) {
        int node = (b << BSH) + n;
        if (node >= NN) break;
        float di = dinv[node];
        float vv = acc[(n << 6) | l] + __half2float(feat[(size_t)node * HID + l]) * di * di;
        if (MODE == 0) {
            vv += b1[l];
            vv = vv > 0.f ? vv : 0.f;
            vv *= mask[(size_t)node * HID + l];
        }
        outp[(size_t)node * HID + l] = (_Float16)vv;
    }
}

// ---- G. out = aggh @ W2 + b2 (fp32) via MFMA: wave = 16 rows x 48(->40) ----
__global__ __launch_bounds__(256) void k_mgemm2(const _Float16* __restrict__ aggh,
                                                const _Float16* __restrict__ w2f,
                                                const float* __restrict__ b2,
                                                float* __restrict__ out) {
    int wid = (blockIdx.x * 256 + threadIdx.x) >> 6;
    int l = threadIdx.x & 63;
    if (wid >= NN / 16) return;
    half8 bf[2][3];
    #pragma unroll
    for (int kk = 0; kk < 2; ++kk)
        #pragma unroll
        for (int n = 0; n < 3; ++n)
            bf[kk][n] = ((const half8*)w2f)[(kk * 3 + n) * 64 + l];
    f32x4 acc[3] = {};
    int arow = wid * 16 + (l & 15);
    const _Float16* hp = aggh + (size_t)arow * HID + (l >> 4) * 8;
    #pragma unroll
    for (int kk = 0; kk < 2; ++kk) {
        half8 af = *(const half8*)(hp + kk * 32);
        #pragma unroll
        for (int n = 0; n < 3; ++n)
            acc[n] = __builtin_amdgcn_mfma_f32_16x16x32_f16(af, bf[kk][n], acc[n], 0, 0, 0);
    }
    int orow = wid * 16 + (l >> 4) * 4;
    int ocol = l & 15;
    #pragma unroll
    for (int n = 0; n < 3; ++n) {
        int col = n * 16 + ocol;
        if (col < OUTD) {
            float bb = b2[col];
            #pragma unroll
            for (int r = 0; r < 4; ++r)
                out[(size_t)(orow + r) * OUTD + col] = acc[n][r] + bb;
        }
    }
}

extern "C" void kernel_launch(void* const* d_in, const int* in_sizes, int n_in,
                              void* d_out, int out_size, void* d_ws, size_t ws_size,
                              hipStream_t stream) {
    const float* x    = (const float*)d_in[0];
    const int*   ei   = (const int*)d_in[1];
    const int*   src  = ei;
    const int*   dst  = ei + NE;
    const float* W1   = (const float*)d_in[2];
    const float* b1   = (const float*)d_in[3];
    const float* W2   = (const float*)d_in[4];
    const float* b2   = (const float*)d_in[5];
    const float* mask = (const float*)d_in[6];
    float* out = (float*)d_out;

    char* ws = (char*)d_ws;
    int*      bfill = (int*)ws;            ws += (size_t)NBKT * 4;
    float*    dinv  = (float*)ws;          ws += (size_t)NN * 4;
    _Float16* w1f   = (_Float16*)ws;       ws += 16 * 64 * 8 * 2;
    _Float16* w2f   = (_Float16*)ws;       ws += 6 * 64 * 8 * 2;
    int2*     csr   = (int2*)ws;           ws += (size_t)NBKT * CAP * 8;   // 16.0 MB
    __half*   h1h   = (__half*)ws;         ws += (size_t)NN * HID * 2;     // 12.8 MB
    _Float16* hh    = (_Float16*)ws;       ws += (size_t)NN * HID * 2;     // 12.8 MB
    int*      pairs = (int*)hh;            // alias: pairs (8 MB) dead before hh written
    _Float16* aggh  = (_Float16*)h1h;      // alias: h1h dead after k_bagg<0>

    hipMemsetAsync(bfill, 0, (size_t)NBKT * 4, stream);

    k_pairs  <<<(NE + CCHUNK - 1) / CCHUNK, 256, 0, stream>>>(src, dst, bfill, pairs);
    k_degdinv<<<NBKT, 256, 0, stream>>>(pairs, bfill, dinv);
    k_csr    <<<NBKT, 256, 0, stream>>>(pairs, bfill, dinv, csr);
    k_wprep  <<<1, 256, 0, stream>>>(W1, W2, w1f, w2f);

    k_mgemm1 <<<(NN / 16 + 3) / 4, 256, 0, stream>>>(x, w1f, h1h);
    k_bagg<0><<<NBKT, 256, 0, stream>>>(csr, bfill, dinv, (const __half*)h1h, b1, mask, hh);
    k_bagg<1><<<NBKT, 256, 0, stream>>>(csr, bfill, dinv, (const __half*)hh, nullptr, nullptr, aggh);
    k_mgemm2 <<<(NN / 16 + 3) / 4, 256, 0, stream>>>(aggh, w2f, b2, out);
}

// Round 11
// 222.268 us; speedup vs baseline: 5.9035x; 5.9035x over previous
//
#include <hip/hip_runtime.h>
#include <hip/hip_fp16.h>

#define NN     100000
#define NE     1600000
#define FEAT   128
#define HID    64
#define OUTD   40
#define BSH    6                          // bucket = dst >> 6 (64 nodes/bucket)
#define BNODES 64
#define NBKT   ((NN + BNODES - 1) / BNODES)   // 1563
#define CAP    1280                       // bucket capacity (mean ~1024, sd ~32)
#define CCHUNK 2048                       // edges per block in pair-scatter
#define WSCALE 262144.0f                  // 2^18 fixed-point scale
#define WINV   (1.0f / 262144.0f)

typedef _Float16 half8 __attribute__((ext_vector_type(8)));
typedef float    f32x4 __attribute__((ext_vector_type(4)));

// ---- A. scatter packed (src<<6|dl) into bucket segments ----
__global__ __launch_bounds__(256) void k_pairs(const int* __restrict__ src,
                                               const int* __restrict__ dst,
                                               int* __restrict__ bfill,
                                               int* __restrict__ pairs) {
    __shared__ int bcnt[NBKT];
    __shared__ int gb[NBKT];
    int t = threadIdx.x;
    for (int i = t; i < NBKT; i += 256) bcnt[i] = 0;
    __syncthreads();
    int e0 = blockIdx.x * CCHUNK;
    int pk[8], bb[8], off[8];
    #pragma unroll
    for (int i = 0; i < 8; ++i) {
        int e = e0 + i * 256 + t;
        if (e < NE) {
            int d = dst[e];
            pk[i]  = (src[e] << BSH) | (d & (BNODES - 1));
            bb[i]  = d >> BSH;
            off[i] = atomicAdd(&bcnt[bb[i]], 1);
        } else bb[i] = -1;
    }
    __syncthreads();
    for (int i = t; i < NBKT; i += 256) {
        int c = bcnt[i];
        gb[i] = c ? (i * CAP + atomicAdd(&bfill[i], c)) : 0;
    }
    __syncthreads();
    #pragma unroll
    for (int i = 0; i < 8; ++i)
        if (bb[i] >= 0) pairs[gb[bb[i]] + off[i]] = pk[i];
}

// ---- B. per-bucket degree hist -> global dinv ----
__global__ __launch_bounds__(256) void k_degdinv(const int* __restrict__ pairs,
                                                 const int* __restrict__ bfill,
                                                 float* __restrict__ dinv) {
    __shared__ int hist[BNODES];
    int b = blockIdx.x, t = threadIdx.x;
    if (t < BNODES) hist[t] = 0;
    __syncthreads();
    int base = b * CAP, count = bfill[b];
    for (int i = t; i < count; i += 256)
        atomicAdd(&hist[pairs[base + i] & (BNODES - 1)], 1);
    __syncthreads();
    int node = (b << BSH) + t;
    if (t < BNODES && node < NN) dinv[node] = rsqrtf((float)hist[t] + 1.0f);
}

// ---- C. per-bucket counting sort by src stripe (src>>9); weights pre-scaled 2^18; pad to 32 ----
__global__ __launch_bounds__(256) void k_csr(const int* __restrict__ pairs,
                                             int* __restrict__ bfill,
                                             const float* __restrict__ dinv,
                                             int2* __restrict__ csr) {
    __shared__ int   hist[256];
    __shared__ int   sc[256];
    __shared__ float ldin[BNODES];
    int b = blockIdx.x, t = threadIdx.x;
    hist[t] = 0;
    if (t < BNODES) {
        int node = (b << BSH) + t;
        ldin[t] = dinv[node < NN ? node : NN - 1];
    }
    __syncthreads();
    int base = b * CAP, count = bfill[b];
    for (int i = t; i < count; i += 256)
        atomicAdd(&hist[(pairs[base + i] >> (BSH + 9)) & 255], 1);
    __syncthreads();
    int v = hist[t];
    sc[t] = v;
    __syncthreads();
    for (int off = 1; off < 256; off <<= 1) {
        int u = (t >= off) ? sc[t - off] : 0;
        __syncthreads();
        sc[t] += u;
        __syncthreads();
    }
    hist[t] = sc[t] - v;          // exclusive prefix; becomes slot-grab counter
    __syncthreads();
    for (int i = t; i < count; i += 256) {
        int p  = pairs[base + i];
        int s  = p >> BSH;
        int dl = p & (BNODES - 1);
        int pos = atomicAdd(&hist[(s >> 9) & 255], 1);
        csr[base + pos] = make_int2(p, __float_as_int(dinv[s] * ldin[dl] * WSCALE));
    }
    int padded = (count + 31) & ~31;
    for (int i = count + t; i < padded; i += 256)
        csr[base + i] = make_int2(0, 0);   // w=0 -> contributes nothing
    __syncthreads();
    if (t == 0) bfill[b] = padded;
}

// ---- D. compress dropout mask {0,2} -> 1 bit/elem ----
__global__ __launch_bounds__(256) void k_maskbits(const float* __restrict__ mask,
                                                  unsigned long long* __restrict__ mb) {
    int node = blockIdx.x * 4 + (threadIdx.x >> 6);
    if (node >= NN) return;
    int l = threadIdx.x & 63;
    float m = mask[(size_t)node * HID + l];
    unsigned long long bits = __ballot(m != 0.f);
    if (l == 0) mb[node] = bits;
}

// ---- E. pack W1/W2 into per-lane MFMA B-fragments (f16) ----
__global__ __launch_bounds__(256) void k_wprep(const float* __restrict__ W1,
                                               const float* __restrict__ W2,
                                               _Float16* __restrict__ w1f,
                                               _Float16* __restrict__ w2f) {
    int t = threadIdx.x;
    for (int it = t; it < 16 * 64; it += 256) {   // W1: kk 0..3 x n 0..3
        int f = it >> 6, l = it & 63;
        int kk = f >> 2, n = f & 3;
        int krow = kk * 32 + (l >> 4) * 8;
        int col  = n * 16 + (l & 15);
        #pragma unroll
        for (int i = 0; i < 8; ++i)
            w1f[it * 8 + i] = (_Float16)W1[(krow + i) * HID + col];
    }
    for (int it = t; it < 6 * 64; it += 256) {    // W2: kk 0..1 x n 0..2 (48-col pad)
        int f = it >> 6, l = it & 63;
        int kk = f / 3, n = f - kk * 3;
        int krow = kk * 32 + (l >> 4) * 8;
        int col  = n * 16 + (l & 15);
        #pragma unroll
        for (int i = 0; i < 8; ++i)
            w2f[it * 8 + i] = (col < OUTD) ? (_Float16)W2[(krow + i) * OUTD + col]
                                           : (_Float16)0.f;
    }
}

// ---- F. h1h = f16(x @ W1) via MFMA: wave = 16 rows x 64 cols ----
__global__ __launch_bounds__(256) void k_mgemm1(const float* __restrict__ x,
                                                const _Float16* __restrict__ w1f,
                                                __half* __restrict__ h1h) {
    int wid = (blockIdx.x * 256 + threadIdx.x) >> 6;
    int l = threadIdx.x & 63;
    if (wid >= NN / 16) return;
    half8 bf[4][4];
    #pragma unroll
    for (int kk = 0; kk < 4; ++kk)
        #pragma unroll
        for (int n = 0; n < 4; ++n)
            bf[kk][n] = ((const half8*)w1f)[(kk * 4 + n) * 64 + l];
    f32x4 acc[4] = {};
    int arow = wid * 16 + (l & 15);
    const float* xp = x + (size_t)arow * FEAT + (l >> 4) * 8;
    #pragma unroll
    for (int kk = 0; kk < 4; ++kk) {
        float4 u0 = *(const float4*)(xp + kk * 32);
        float4 u1 = *(const float4*)(xp + kk * 32 + 4);
        half8 af;
        af[0] = (_Float16)u0.x; af[1] = (_Float16)u0.y;
        af[2] = (_Float16)u0.z; af[3] = (_Float16)u0.w;
        af[4] = (_Float16)u1.x; af[5] = (_Float16)u1.y;
        af[6] = (_Float16)u1.z; af[7] = (_Float16)u1.w;
        #pragma unroll
        for (int n = 0; n < 4; ++n)
            acc[n] = __builtin_amdgcn_mfma_f32_16x16x32_f16(af, bf[kk][n], acc[n], 0, 0, 0);
    }
    int orow = wid * 16 + (l >> 4) * 4;
    int ocol = l & 15;
    #pragma unroll
    for (int n = 0; n < 4; ++n)
        #pragma unroll
        for (int r = 0; r < 4; ++r)
            h1h[(size_t)(orow + r) * HID + n * 16 + ocol] = __float2half(acc[n][r]);
}

// ---- G. block-per-bucket edge-parallel aggregation, LDS INT (2^18 fixed-point) accumulator ----
// MODE 0: relu(agg + self + b1) * mask -> outp ; MODE 1: agg + self -> outp
template<int MODE>
__global__ __launch_bounds__(256) void k_bagg(const int2* __restrict__ csr,
                                              const int* __restrict__ bfill,
                                              const float* __restrict__ dinv,
                                              const __half* __restrict__ feat,
                                              const float* __restrict__ b1,
                                              const unsigned long long* __restrict__ maskbits,
                                              _Float16* __restrict__ outp) {
    __shared__ int acc[BNODES * HID];     // 16 KB -> 8 blocks/CU
    int t = threadIdx.x, wv = t >> 6, l = t & 63;
    int b = blockIdx.x;
    int4* a4 = (int4*)acc;
    for (int i = t; i < BNODES * HID / 4; i += 256) a4[i] = make_int4(0, 0, 0, 0);
    __syncthreads();
    int base = b * CAP;
    int count = bfill[b];                 // padded to multiple of 32
    for (int j = wv * 4; j < count; j += 16) {
        int2 e0 = csr[base + j + 0];
        int2 e1 = csr[base + j + 1];
        int2 e2 = csr[base + j + 2];
        int2 e3 = csr[base + j + 3];
        int v0 = (int)(__half2float(feat[(size_t)(e0.x >> BSH) * HID + l]) * __int_as_float(e0.y));
        int v1 = (int)(__half2float(feat[(size_t)(e1.x >> BSH) * HID + l]) * __int_as_float(e1.y));
        int v2 = (int)(__half2float(feat[(size_t)(e2.x >> BSH) * HID + l]) * __int_as_float(e2.y));
        int v3 = (int)(__half2float(feat[(size_t)(e3.x >> BSH) * HID + l]) * __int_as_float(e3.y));
        atomicAdd(&acc[((e0.x & (BNODES - 1)) << 6) | l], v0);
        atomicAdd(&acc[((e1.x & (BNODES - 1)) << 6) | l], v1);
        atomicAdd(&acc[((e2.x & (BNODES - 1)) << 6) | l], v2);
        atomicAdd(&acc[((e3.x & (BNODES - 1)) << 6) | l], v3);
    }
    __syncthreads();
    for (int n = wv; n < BNODES; n += 4) {
        int node = (b << BSH) + n;
        if (node >= NN) break;
        float di = dinv[node];
        float vv = (float)acc[(n << 6) | l] * WINV
                 + __half2float(feat[(size_t)node * HID + l]) * di * di;
        if (MODE == 0) {
            vv += b1[l];
            vv = vv > 0.f ? vv : 0.f;
            unsigned long long mb = maskbits[node];
            vv *= ((mb >> l) & 1ull) ? 2.0f : 0.0f;
        }
        outp[(size_t)node * HID + l] = (_Float16)vv;
    }
}

// ---- H. out = aggh @ W2 + b2 (fp32) via MFMA: wave = 16 rows x 48(->40) ----
__global__ __launch_bounds__(256) void k_mgemm2(const _Float16* __restrict__ aggh,
                                                const _Float16* __restrict__ w2f,
                                                const float* __restrict__ b2,
                                                float* __restrict__ out) {
    int wid = (blockIdx.x * 256 + threadIdx.x) >> 6;
    int l = threadIdx.x & 63;
    if (wid >= NN / 16) return;
    half8 bf[2][3];
    #pragma unroll
    for (int kk = 0; kk < 2; ++kk)
        #pragma unroll
        for (int n = 0; n < 3; ++n)
            bf[kk][n] = ((const half8*)w2f)[(kk * 3 + n) * 64 + l];
    f32x4 acc[3] = {};
    int arow = wid * 16 + (l & 15);
    const _Float16* hp = aggh + (size_t)arow * HID + (l >> 4) * 8;
    #pragma unroll
    for (int kk = 0; kk < 2; ++kk) {
        half8 af = *(const half8*)(hp + kk * 32);
        #pragma unroll
        for (int n = 0; n < 3; ++n)
            acc[n] = __builtin_amdgcn_mfma_f32_16x16x32_f16(af, bf[kk][n], acc[n], 0, 0, 0);
    }
    int orow = wid * 16 + (l >> 4) * 4;
    int ocol = l & 15;
    #pragma unroll
    for (int n = 0; n < 3; ++n) {
        int col = n * 16 + ocol;
        if (col < OUTD) {
            float bb = b2[col];
            #pragma unroll
            for (int r = 0; r < 4; ++r)
                out[(size_t)(orow + r) * OUTD + col] = acc[n][r] + bb;
        }
    }
}

extern "C" void kernel_launch(void* const* d_in, const int* in_sizes, int n_in,
                              void* d_out, int out_size, void* d_ws, size_t ws_size,
                              hipStream_t stream) {
    const float* x    = (const float*)d_in[0];
    const int*   ei   = (const int*)d_in[1];
    const int*   src  = ei;
    const int*   dst  = ei + NE;
    const float* W1   = (const float*)d_in[2];
    const float* b1   = (const float*)d_in[3];
    const float* W2   = (const float*)d_in[4];
    const float* b2   = (const float*)d_in[5];
    const float* mask = (const float*)d_in[6];
    float* out = (float*)d_out;

    char* ws = (char*)d_ws;
    int*      bfill = (int*)ws;            ws += (size_t)NBKT * 4;
    float*    dinv  = (float*)ws;          ws += (size_t)NN * 4;
    unsigned long long* maskb = (unsigned long long*)ws; ws += (size_t)NN * 8;
    _Float16* w1f   = (_Float16*)ws;       ws += 16 * 64 * 8 * 2;
    _Float16* w2f   = (_Float16*)ws;       ws += 6 * 64 * 8 * 2;
    int2*     csr   = (int2*)ws;           ws += (size_t)NBKT * CAP * 8;   // 16.0 MB
    __half*   h1h   = (__half*)ws;         ws += (size_t)NN * HID * 2;     // 12.8 MB
    _Float16* hh    = (_Float16*)ws;       ws += (size_t)NN * HID * 2;     // 12.8 MB
    int*      pairs = (int*)hh;            // alias: pairs (8 MB) dead before hh written
    _Float16* aggh  = (_Float16*)h1h;      // alias: h1h dead after k_bagg<0>

    hipMemsetAsync(bfill, 0, (size_t)NBKT * 4, stream);

    k_pairs   <<<(NE + CCHUNK - 1) / CCHUNK, 256, 0, stream>>>(src, dst, bfill, pairs);
    k_degdinv <<<NBKT, 256, 0, stream>>>(pairs, bfill, dinv);
    k_csr     <<<NBKT, 256, 0, stream>>>(pairs, bfill, dinv, csr);
    k_maskbits<<<(NN + 3) / 4, 256, 0, stream>>>(mask, maskb);
    k_wprep   <<<1, 256, 0, stream>>>(W1, W2, w1f, w2f);

    k_mgemm1  <<<(NN / 16 + 3) / 4, 256, 0, stream>>>(x, w1f, h1h);
    k_bagg<0> <<<NBKT, 256, 0, stream>>>(csr, bfill, dinv, (const __half*)h1h, b1, maskb, hh);
    k_bagg<1> <<<NBKT, 256, 0, stream>>>(csr, bfill, dinv, (const __half*)hh, nullptr, nullptr, aggh);
    k_mgemm2  <<<(NN / 16 + 3) / 4, 256, 0, stream>>>(aggh, w2f, b2, out);
}

// Round 12
// 195.904 us; speedup vs baseline: 6.6979x; 1.1346x over previous
//
#include <hip/hip_runtime.h>
#include <hip/hip_fp16.h>

#define NN     100000
#define NE     1600000
#define FEAT   128
#define HID    64
#define OUTD   40
#define BSH    5                          // bucket = dst >> 5 (32 nodes/bucket)
#define BNODES 32
#define NBKT   (NN / BNODES)              // 3125 (exact)
#define CAP    768                        // bucket capacity (mean 512, sd ~23; mult of 32)
#define CCHUNK 2048                       // edges per block in pair-scatter
#define WSCALE 262144.0f                  // 2^18 fixed-point scale
#define WINV   (1.0f / 262144.0f)

typedef _Float16 half8 __attribute__((ext_vector_type(8)));
typedef float    f32x4 __attribute__((ext_vector_type(4)));

// ---- A. scatter packed ex=(src<<7|dl) into bucket segments ----
__global__ __launch_bounds__(256) void k_pairs(const int* __restrict__ src,
                                               const int* __restrict__ dst,
                                               int* __restrict__ bfill,
                                               int* __restrict__ pairs) {
    __shared__ int bcnt[NBKT];
    __shared__ int gb[NBKT];
    int t = threadIdx.x;
    for (int i = t; i < NBKT; i += 256) bcnt[i] = 0;
    __syncthreads();
    int e0 = blockIdx.x * CCHUNK;
    int pk[8], bb[8], off[8];
    #pragma unroll
    for (int i = 0; i < 8; ++i) {
        int e = e0 + i * 256 + t;
        if (e < NE) {
            int d = dst[e];
            pk[i]  = (src[e] << 7) | (d & (BNODES - 1));
            bb[i]  = d >> BSH;
            off[i] = atomicAdd(&bcnt[bb[i]], 1);
        } else bb[i] = -1;
    }
    __syncthreads();
    for (int i = t; i < NBKT; i += 256) {
        int c = bcnt[i];
        gb[i] = c ? (i * CAP + atomicAdd(&bfill[i], c)) : 0;
    }
    __syncthreads();
    #pragma unroll
    for (int i = 0; i < 8; ++i)
        if (bb[i] >= 0) pairs[gb[bb[i]] + off[i]] = pk[i];
}

// ---- B. per-bucket degree hist -> global dinv ----
__global__ __launch_bounds__(256) void k_degdinv(const int* __restrict__ pairs,
                                                 const int* __restrict__ bfill,
                                                 float* __restrict__ dinv) {
    __shared__ int hist[BNODES];
    int b = blockIdx.x, t = threadIdx.x;
    if (t < BNODES) hist[t] = 0;
    __syncthreads();
    int base = b * CAP, count = bfill[b];
    for (int i = t; i < count; i += 256)
        atomicAdd(&hist[pairs[base + i] & (BNODES - 1)], 1);
    __syncthreads();
    if (t < BNODES) dinv[(b << BSH) + t] = rsqrtf((float)hist[t] + 1.0f);
}

// ---- C. per-bucket counting sort by src stripe (ex>>16); zero-pad -> row NN ----
__global__ __launch_bounds__(256) void k_csr(const int* __restrict__ pairs,
                                             int* __restrict__ bfill,
                                             int* __restrict__ csr) {
    __shared__ int hist[256];
    __shared__ int sc[256];
    int b = blockIdx.x, t = threadIdx.x;
    hist[t] = 0;
    __syncthreads();
    int base = b * CAP, count = bfill[b];
    for (int i = t; i < count; i += 256)
        atomicAdd(&hist[(pairs[base + i] >> 16) & 255], 1);
    __syncthreads();
    int v = hist[t];
    sc[t] = v;
    __syncthreads();
    for (int off = 1; off < 256; off <<= 1) {
        int u = (t >= off) ? sc[t - off] : 0;
        __syncthreads();
        sc[t] += u;
        __syncthreads();
    }
    hist[t] = sc[t] - v;          // exclusive prefix; becomes slot-grab counter
    __syncthreads();
    for (int i = t; i < count; i += 256) {
        int p = pairs[base + i];
        int pos = atomicAdd(&hist[(p >> 16) & 255], 1);
        csr[base + pos] = p;
    }
    int padded = (count + 31) & ~31;
    for (int i = count + t; i < padded; i += 256)
        csr[base + i] = (NN << 7);         // gathers zeroed row NN, dl=0
    __syncthreads();
    if (t == 0) bfill[b] = padded;
}

// ---- D. compress dropout mask {0,2} -> 1 bit/elem ----
__global__ __launch_bounds__(256) void k_maskbits(const float* __restrict__ mask,
                                                  unsigned long long* __restrict__ mb) {
    int node = blockIdx.x * 4 + (threadIdx.x >> 6);
    if (node >= NN) return;
    int l = threadIdx.x & 63;
    float m = mask[(size_t)node * HID + l];
    unsigned long long bits = __ballot(m != 0.f);
    if (l == 0) mb[node] = bits;
}

// ---- E. pack W1/W2 into per-lane MFMA B-fragments (f16); zero pad rows NN ----
__global__ __launch_bounds__(256) void k_wprep(const float* __restrict__ W1,
                                               const float* __restrict__ W2,
                                               _Float16* __restrict__ w1f,
                                               _Float16* __restrict__ w2f,
                                               __half* __restrict__ h1s,
                                               __half* __restrict__ hhs) {
    int t = threadIdx.x;
    for (int it = t; it < 16 * 64; it += 256) {   // W1: kk 0..3 x n 0..3
        int f = it >> 6, l = it & 63;
        int kk = f >> 2, n = f & 3;
        int krow = kk * 32 + (l >> 4) * 8;
        int col  = n * 16 + (l & 15);
        #pragma unroll
        for (int i = 0; i < 8; ++i)
            w1f[it * 8 + i] = (_Float16)W1[(krow + i) * HID + col];
    }
    for (int it = t; it < 6 * 64; it += 256) {    // W2: kk 0..1 x n 0..2 (48-col pad)
        int f = it >> 6, l = it & 63;
        int kk = f / 3, n = f - kk * 3;
        int krow = kk * 32 + (l >> 4) * 8;
        int col  = n * 16 + (l & 15);
        #pragma unroll
        for (int i = 0; i < 8; ++i)
            w2f[it * 8 + i] = (col < OUTD) ? (_Float16)W2[(krow + i) * OUTD + col]
                                           : (_Float16)0.f;
    }
    if (t < HID) {                                 // zero the padding row NN
        h1s[(size_t)NN * HID + t] = __float2half(0.f);
        hhs[(size_t)NN * HID + t] = __float2half(0.f);
    }
}

// ---- F. h1s = f16((x @ W1) * dinv[row]) via MFMA ----
__global__ __launch_bounds__(256) void k_mgemm1(const float* __restrict__ x,
                                                const _Float16* __restrict__ w1f,
                                                const float* __restrict__ dinv,
                                                __half* __restrict__ h1s) {
    int wid = (blockIdx.x * 256 + threadIdx.x) >> 6;
    int l = threadIdx.x & 63;
    if (wid >= NN / 16) return;
    half8 bf[4][4];
    #pragma unroll
    for (int kk = 0; kk < 4; ++kk)
        #pragma unroll
        for (int n = 0; n < 4; ++n)
            bf[kk][n] = ((const half8*)w1f)[(kk * 4 + n) * 64 + l];
    f32x4 acc[4] = {};
    int arow = wid * 16 + (l & 15);
    const float* xp = x + (size_t)arow * FEAT + (l >> 4) * 8;
    #pragma unroll
    for (int kk = 0; kk < 4; ++kk) {
        float4 u0 = *(const float4*)(xp + kk * 32);
        float4 u1 = *(const float4*)(xp + kk * 32 + 4);
        half8 af;
        af[0] = (_Float16)u0.x; af[1] = (_Float16)u0.y;
        af[2] = (_Float16)u0.z; af[3] = (_Float16)u0.w;
        af[4] = (_Float16)u1.x; af[5] = (_Float16)u1.y;
        af[6] = (_Float16)u1.z; af[7] = (_Float16)u1.w;
        #pragma unroll
        for (int n = 0; n < 4; ++n)
            acc[n] = __builtin_amdgcn_mfma_f32_16x16x32_f16(af, bf[kk][n], acc[n], 0, 0, 0);
    }
    int orow = wid * 16 + (l >> 4) * 4;
    int ocol = l & 15;
    float dv[4];
    #pragma unroll
    for (int r = 0; r < 4; ++r) dv[r] = dinv[orow + r];
    #pragma unroll
    for (int n = 0; n < 4; ++n)
        #pragma unroll
        for (int r = 0; r < 4; ++r)
            h1s[(size_t)(orow + r) * HID + n * 16 + ocol] = __float2half(acc[n][r] * dv[r]);
}

// ---- G. block-per-bucket edge sweep, LDS int accumulator; feats pre-scaled by dinv[src] ----
// MODE 0: hh_s = f16(relu((acc+self)*di + b1) * mask * di) ; MODE 1: aggh = f16((acc+self)*di)
template<int MODE>
__global__ __launch_bounds__(256) void k_bagg(const int* __restrict__ csr,
                                              const int* __restrict__ bfill,
                                              const float* __restrict__ dinv,
                                              const __half* __restrict__ feat,
                                              const float* __restrict__ b1,
                                              const unsigned long long* __restrict__ maskbits,
                                              __half* __restrict__ outp) {
    __shared__ int acc[BNODES * HID];     // 8 KB -> 8 blocks/CU (thread-capped)
    int t = threadIdx.x, wv = t >> 6, l = t & 63;
    int b = blockIdx.x;
    int4* a4 = (int4*)acc;
    for (int i = t; i < BNODES * HID / 4; i += 256) a4[i] = make_int4(0, 0, 0, 0);
    __syncthreads();
    int base = b * CAP;
    int count = bfill[b];                 // multiple of 32
    const char* fb = (const char*)feat + ((size_t)l * 2);
    for (int j = wv * 8; j < count; j += 32) {
        int e0 = csr[base + j + 0], e1 = csr[base + j + 1];
        int e2 = csr[base + j + 2], e3 = csr[base + j + 3];
        int e4 = csr[base + j + 4], e5 = csr[base + j + 5];
        int e6 = csr[base + j + 6], e7 = csr[base + j + 7];
        float a0 = __half2float(*(const __half*)(fb + (unsigned)(e0 & ~127)));
        float a1 = __half2float(*(const __half*)(fb + (unsigned)(e1 & ~127)));
        float a2 = __half2float(*(const __half*)(fb + (unsigned)(e2 & ~127)));
        float a3 = __half2float(*(const __half*)(fb + (unsigned)(e3 & ~127)));
        float a4v = __half2float(*(const __half*)(fb + (unsigned)(e4 & ~127)));
        float a5 = __half2float(*(const __half*)(fb + (unsigned)(e5 & ~127)));
        float a6 = __half2float(*(const __half*)(fb + (unsigned)(e6 & ~127)));
        float a7 = __half2float(*(const __half*)(fb + (unsigned)(e7 & ~127)));
        atomicAdd(&acc[((e0 & 31) << 6) + l], (int)(a0 * WSCALE));
        atomicAdd(&acc[((e1 & 31) << 6) + l], (int)(a1 * WSCALE));
        atomicAdd(&acc[((e2 & 31) << 6) + l], (int)(a2 * WSCALE));
        atomicAdd(&acc[((e3 & 31) << 6) + l], (int)(a3 * WSCALE));
        atomicAdd(&acc[((e4 & 31) << 6) + l], (int)(a4v * WSCALE));
        atomicAdd(&acc[((e5 & 31) << 6) + l], (int)(a5 * WSCALE));
        atomicAdd(&acc[((e6 & 31) << 6) + l], (int)(a6 * WSCALE));
        atomicAdd(&acc[((e7 & 31) << 6) + l], (int)(a7 * WSCALE));
    }
    __syncthreads();
    for (int n = wv; n < BNODES; n += 4) {
        int node = (b << BSH) + n;
        float di = dinv[node];
        float selfv = __half2float(feat[(size_t)node * HID + l]);
        float vv = ((float)acc[(n << 6) + l] * WINV + selfv) * di;
        if (MODE == 0) {
            vv += b1[l];
            vv = vv > 0.f ? vv : 0.f;
            unsigned long long mb = maskbits[node];
            vv = ((mb >> l) & 1ull) ? vv * 2.0f * di : 0.0f;
        }
        outp[(size_t)node * HID + l] = __float2half(vv);
    }
}

// ---- H. out = aggh @ W2 + b2 (fp32) via MFMA ----
__global__ __launch_bounds__(256) void k_mgemm2(const __half* __restrict__ aggh,
                                                const _Float16* __restrict__ w2f,
                                                const float* __restrict__ b2,
                                                float* __restrict__ out) {
    int wid = (blockIdx.x * 256 + threadIdx.x) >> 6;
    int l = threadIdx.x & 63;
    if (wid >= NN / 16) return;
    half8 bf[2][3];
    #pragma unroll
    for (int kk = 0; kk < 2; ++kk)
        #pragma unroll
        for (int n = 0; n < 3; ++n)
            bf[kk][n] = ((const half8*)w2f)[(kk * 3 + n) * 64 + l];
    f32x4 acc[3] = {};
    int arow = wid * 16 + (l & 15);
    const _Float16* hp = (const _Float16*)aggh + (size_t)arow * HID + (l >> 4) * 8;
    #pragma unroll
    for (int kk = 0; kk < 2; ++kk) {
        half8 af = *(const half8*)(hp + kk * 32);
        #pragma unroll
        for (int n = 0; n < 3; ++n)
            acc[n] = __builtin_amdgcn_mfma_f32_16x16x32_f16(af, bf[kk][n], acc[n], 0, 0, 0);
    }
    int orow = wid * 16 + (l >> 4) * 4;
    int ocol = l & 15;
    #pragma unroll
    for (int n = 0; n < 3; ++n) {
        int col = n * 16 + ocol;
        if (col < OUTD) {
            float bb = b2[col];
            #pragma unroll
            for (int r = 0; r < 4; ++r)
                out[(size_t)(orow + r) * OUTD + col] = acc[n][r] + bb;
        }
    }
}

extern "C" void kernel_launch(void* const* d_in, const int* in_sizes, int n_in,
                              void* d_out, int out_size, void* d_ws, size_t ws_size,
                              hipStream_t stream) {
    const float* x    = (const float*)d_in[0];
    const int*   ei   = (const int*)d_in[1];
    const int*   src  = ei;
    const int*   dst  = ei + NE;
    const float* W1   = (const float*)d_in[2];
    const float* b1   = (const float*)d_in[3];
    const float* W2   = (const float*)d_in[4];
    const float* b2   = (const float*)d_in[5];
    const float* mask = (const float*)d_in[6];
    float* out = (float*)d_out;

    char* ws = (char*)d_ws;
    int*      bfill = (int*)ws;            ws += (size_t)NBKT * 4;
    float*    dinv  = (float*)ws;          ws += (size_t)NN * 4;
    unsigned long long* maskb = (unsigned long long*)ws; ws += (size_t)NN * 8;
    _Float16* w1f   = (_Float16*)ws;       ws += 16 * 64 * 8 * 2;
    _Float16* w2f   = (_Float16*)ws;       ws += 6 * 64 * 8 * 2;
    int*      csr   = (int*)ws;            ws += (size_t)NBKT * CAP * 4;       // 9.6 MB
    __half*   h1s   = (__half*)ws;         ws += (size_t)(NN + 1) * HID * 2;   // 12.8 MB
    __half*   hhs   = (__half*)ws;         ws += (size_t)(NN + 1) * HID * 2;   // 12.8 MB
    int*      pairs = (int*)hhs;           // alias: pairs (9.6 MB) dead before hhs rows written
    __half*   aggh  = h1s;                 // alias: h1s dead after k_bagg<0>

    hipMemsetAsync(bfill, 0, (size_t)NBKT * 4, stream);

    k_pairs   <<<(NE + CCHUNK - 1) / CCHUNK, 256, 0, stream>>>(src, dst, bfill, pairs);
    k_degdinv <<<NBKT, 256, 0, stream>>>(pairs, bfill, dinv);
    k_csr     <<<NBKT, 256, 0, stream>>>(pairs, bfill, csr);
    k_maskbits<<<(NN + 3) / 4, 256, 0, stream>>>(mask, maskb);
    k_wprep   <<<1, 256, 0, stream>>>(W1, W2, w1f, w2f, h1s, hhs);

    k_mgemm1  <<<(NN / 16 + 3) / 4, 256, 0, stream>>>(x, w1f, dinv, h1s);
    k_bagg<0> <<<NBKT, 256, 0, stream>>>(csr, bfill, dinv, h1s, b1, maskb, hhs);
    k_bagg<1> <<<NBKT, 256, 0, stream>>>(csr, bfill, dinv, hhs, nullptr, nullptr, aggh);
    k_mgemm2  <<<(NN / 16 + 3) / 4, 256, 0, stream>>>(aggh, w2f, b2, out);
}

// Round 13
// 181.496 us; speedup vs baseline: 7.2297x; 1.0794x over previous
//
#include <hip/hip_runtime.h>
#include <hip/hip_fp16.h>

#define NN     100000
#define NE     1600000
#define FEAT   128
#define HID    64
#define OUTD   40
#define BNODES 32                         // aggregation bucket = 32 dst nodes
#define NSB    ((NN + 255) / 256)         // 391 superbuckets of 256 nodes
#define NBAGG  (NSB * 8)                  // 3128 aggregation buckets
#define CAP    5120                       // superbucket capacity (mean 4096, sd ~64)
#define CCHUNK 2048                       // edges per block in pair-scatter
#define WSCALE 262144.0f                  // 2^18 fixed-point scale
#define WINV   (1.0f / 262144.0f)

typedef _Float16 half8 __attribute__((ext_vector_type(8)));
typedef float    f32x4 __attribute__((ext_vector_type(4)));

// ---- A. scatter packed ex=(src<<8|dl) into superbucket segments ----
__global__ __launch_bounds__(256) void k_pairs(const int* __restrict__ src,
                                               const int* __restrict__ dst,
                                               int* __restrict__ bfill,
                                               int* __restrict__ pairs) {
    __shared__ int bcnt[NSB];
    __shared__ int gb[NSB];
    int t = threadIdx.x;
    for (int i = t; i < NSB; i += 256) bcnt[i] = 0;
    __syncthreads();
    int e0 = blockIdx.x * CCHUNK;
    int pk[8], bb[8], off[8];
    #pragma unroll
    for (int i = 0; i < 8; ++i) {
        int e = e0 + i * 256 + t;
        if (e < NE) {
            int d = dst[e];
            pk[i]  = (src[e] << 8) | (d & 255);
            bb[i]  = d >> 8;
            off[i] = atomicAdd(&bcnt[bb[i]], 1);
        } else bb[i] = -1;
    }
    __syncthreads();
    for (int i = t; i < NSB; i += 256) {
        int c = bcnt[i];
        gb[i] = c ? (i * CAP + atomicAdd(&bfill[i], c)) : 0;
    }
    __syncthreads();
    #pragma unroll
    for (int i = 0; i < 8; ++i)
        if (bb[i] >= 0) pairs[gb[bb[i]] + off[i]] = pk[i];
}

// ---- B. per-superbucket degree hist -> global dinv ----
__global__ __launch_bounds__(256) void k_degdinv(const int* __restrict__ pairs,
                                                 const int* __restrict__ bfill,
                                                 float* __restrict__ dinv) {
    __shared__ int hist[256];
    int b = blockIdx.x, t = threadIdx.x;
    hist[t] = 0;
    __syncthreads();
    int base = b * CAP, count = bfill[b];
    for (int i = t; i < count; i += 256)
        atomicAdd(&hist[pairs[base + i] & 255], 1);
    __syncthreads();
    int node = (b << 8) + t;
    if (node < NN) dinv[node] = rsqrtf((float)hist[t] + 1.0f);
}

// ---- C. per-superbucket counting sort by (subbucket, src-stripe); padded sub-segments ----
__global__ __launch_bounds__(256) void k_csr(const int* __restrict__ pairs,
                                             const int* __restrict__ bfill,
                                             int* __restrict__ sb_beg,
                                             int* __restrict__ sb_cnt,
                                             int* __restrict__ csr) {
    __shared__ int hist[2048];
    __shared__ int exs[2048];
    __shared__ int part[256];
    __shared__ int poff[9];
    __shared__ int sstart[8];
    __shared__ int dtot[8];
    int b = blockIdx.x, t = threadIdx.x;
    #pragma unroll
    for (int k = 0; k < 8; ++k) hist[t * 8 + k] = 0;
    __syncthreads();
    int base = b * CAP, count = bfill[b];
    for (int i = t; i < count; i += 256) {
        int p = pairs[base + i];
        int key = (((p & 255) >> 5) << 8) | ((p >> 17) & 255);
        atomicAdd(&hist[key], 1);
    }
    __syncthreads();
    int loc[8], s0 = 0;
    #pragma unroll
    for (int k = 0; k < 8; ++k) { loc[k] = s0; s0 += hist[t * 8 + k]; }
    part[t] = s0;
    __syncthreads();
    for (int off = 1; off < 256; off <<= 1) {
        int u = (t >= off) ? part[t - off] : 0;
        __syncthreads();
        part[t] += u;
        __syncthreads();
    }
    int pex = part[t] - s0;
    #pragma unroll
    for (int k = 0; k < 8; ++k) exs[t * 8 + k] = pex + loc[k];
    __syncthreads();
    if (t < 8) {
        sstart[t] = exs[t * 256];
        int end = (t == 7) ? count : exs[(t + 1) * 256];
        dtot[t] = end - sstart[t];
    }
    __syncthreads();
    if (t == 0) {
        poff[0] = 0;
        for (int d = 0; d < 8; ++d) poff[d + 1] = poff[d] + ((dtot[d] + 31) & ~31);
    }
    __syncthreads();
    #pragma unroll
    for (int k = 0; k < 8; ++k) {
        int key = t * 8 + k;
        int d = key >> 8;
        exs[key] = poff[d] + (exs[key] - sstart[d]);
        hist[key] = 0;
    }
    __syncthreads();
    for (int i = t; i < count; i += 256) {
        int p = pairs[base + i];
        int key = (((p & 255) >> 5) << 8) | ((p >> 17) & 255);
        int pos = exs[key] + atomicAdd(&hist[key], 1);
        csr[base + pos] = ((p >> 8) << 7) | (p & 31);   // (src<<7)|dl5
    }
    for (int d = 0; d < 8; ++d) {
        int padded = (dtot[d] + 31) & ~31;
        for (int i = dtot[d] + t; i < padded; i += 256)
            csr[base + poff[d] + i] = (NN << 7);        // gathers zeroed row NN
    }
    if (t < 8) {
        sb_beg[b * 8 + t] = base + poff[t];
        sb_cnt[b * 8 + t] = (dtot[t] + 31) & ~31;
    }
}

// ---- D. compress dropout mask {0,2} -> 1 bit/elem ----
__global__ __launch_bounds__(256) void k_maskbits(const float* __restrict__ mask,
                                                  unsigned long long* __restrict__ mb) {
    int node = blockIdx.x * 4 + (threadIdx.x >> 6);
    if (node >= NN) return;
    int l = threadIdx.x & 63;
    float m = mask[(size_t)node * HID + l];
    unsigned long long bits = __ballot(m != 0.f);
    if (l == 0) mb[node] = bits;
}

// ---- E. pack W1/W2 into per-lane MFMA B-fragments (f16); zero pad rows NN ----
__global__ __launch_bounds__(256) void k_wprep(const float* __restrict__ W1,
                                               const float* __restrict__ W2,
                                               _Float16* __restrict__ w1f,
                                               _Float16* __restrict__ w2f,
                                               __half* __restrict__ h1s,
                                               __half* __restrict__ hhs) {
    int t = threadIdx.x;
    for (int it = t; it < 16 * 64; it += 256) {   // W1: kk 0..3 x n 0..3
        int f = it >> 6, l = it & 63;
        int kk = f >> 2, n = f & 3;
        int krow = kk * 32 + (l >> 4) * 8;
        int col  = n * 16 + (l & 15);
        #pragma unroll
        for (int i = 0; i < 8; ++i)
            w1f[it * 8 + i] = (_Float16)W1[(krow + i) * HID + col];
    }
    for (int it = t; it < 6 * 64; it += 256) {    // W2: kk 0..1 x n 0..2 (48-col pad)
        int f = it >> 6, l = it & 63;
        int kk = f / 3, n = f - kk * 3;
        int krow = kk * 32 + (l >> 4) * 8;
        int col  = n * 16 + (l & 15);
        #pragma unroll
        for (int i = 0; i < 8; ++i)
            w2f[it * 8 + i] = (col < OUTD) ? (_Float16)W2[(krow + i) * OUTD + col]
                                           : (_Float16)0.f;
    }
    if (t < HID) {                                 // zero the padding row NN
        h1s[(size_t)NN * HID + t] = __float2half(0.f);
        hhs[(size_t)NN * HID + t] = __float2half(0.f);
    }
}

// ---- F. h1s = f16((x @ W1) * dinv[row]) via MFMA ----
__global__ __launch_bounds__(256) void k_mgemm1(const float* __restrict__ x,
                                                const _Float16* __restrict__ w1f,
                                                const float* __restrict__ dinv,
                                                __half* __restrict__ h1s) {
    int wid = (blockIdx.x * 256 + threadIdx.x) >> 6;
    int l = threadIdx.x & 63;
    if (wid >= NN / 16) return;
    half8 bf[4][4];
    #pragma unroll
    for (int kk = 0; kk < 4; ++kk)
        #pragma unroll
        for (int n = 0; n < 4; ++n)
            bf[kk][n] = ((const half8*)w1f)[(kk * 4 + n) * 64 + l];
    f32x4 acc[4] = {};
    int arow = wid * 16 + (l & 15);
    const float* xp = x + (size_t)arow * FEAT + (l >> 4) * 8;
    #pragma unroll
    for (int kk = 0; kk < 4; ++kk) {
        float4 u0 = *(const float4*)(xp + kk * 32);
        float4 u1 = *(const float4*)(xp + kk * 32 + 4);
        half8 af;
        af[0] = (_Float16)u0.x; af[1] = (_Float16)u0.y;
        af[2] = (_Float16)u0.z; af[3] = (_Float16)u0.w;
        af[4] = (_Float16)u1.x; af[5] = (_Float16)u1.y;
        af[6] = (_Float16)u1.z; af[7] = (_Float16)u1.w;
        #pragma unroll
        for (int n = 0; n < 4; ++n)
            acc[n] = __builtin_amdgcn_mfma_f32_16x16x32_f16(af, bf[kk][n], acc[n], 0, 0, 0);
    }
    int orow = wid * 16 + (l >> 4) * 4;
    int ocol = l & 15;
    float dv[4];
    #pragma unroll
    for (int r = 0; r < 4; ++r) dv[r] = dinv[orow + r];
    #pragma unroll
    for (int n = 0; n < 4; ++n)
        #pragma unroll
        for (int r = 0; r < 4; ++r)
            h1s[(size_t)(orow + r) * HID + n * 16 + ocol] = __float2half(acc[n][r] * dv[r]);
}

// ---- G. block-per-subbucket edge sweep, LDS int accumulator; feats pre-scaled by dinv[src] ----
// MODE 0: hh_s = f16(relu((acc+self)*di + b1) * mask * di) ; MODE 1: aggh = f16((acc+self)*di)
template<int MODE>
__global__ __launch_bounds__(256) void k_bagg(const int* __restrict__ csr,
                                              const int* __restrict__ sb_beg,
                                              const int* __restrict__ sb_cnt,
                                              const float* __restrict__ dinv,
                                              const __half* __restrict__ feat,
                                              const float* __restrict__ b1,
                                              const unsigned long long* __restrict__ maskbits,
                                              __half* __restrict__ outp) {
    __shared__ int acc[BNODES * HID];     // 8 KB
    int t = threadIdx.x, wv = t >> 6, l = t & 63;
    int bb = blockIdx.x;
    int4* a4 = (int4*)acc;
    for (int i = t; i < BNODES * HID / 4; i += 256) a4[i] = make_int4(0, 0, 0, 0);
    __syncthreads();
    int base  = sb_beg[bb];
    int count = sb_cnt[bb];               // multiple of 32
    int node0 = (bb >> 3) * 256 + (bb & 7) * 32;
    const char* fb = (const char*)feat + ((size_t)l * 2);
    for (int j = wv * 8; j < count; j += 32) {
        int e0 = csr[base + j + 0], e1 = csr[base + j + 1];
        int e2 = csr[base + j + 2], e3 = csr[base + j + 3];
        int e4 = csr[base + j + 4], e5 = csr[base + j + 5];
        int e6 = csr[base + j + 6], e7 = csr[base + j + 7];
        float a0 = __half2float(*(const __half*)(fb + (unsigned)(e0 & ~127)));
        float a1 = __half2float(*(const __half*)(fb + (unsigned)(e1 & ~127)));
        float a2 = __half2float(*(const __half*)(fb + (unsigned)(e2 & ~127)));
        float a3 = __half2float(*(const __half*)(fb + (unsigned)(e3 & ~127)));
        float a4v = __half2float(*(const __half*)(fb + (unsigned)(e4 & ~127)));
        float a5 = __half2float(*(const __half*)(fb + (unsigned)(e5 & ~127)));
        float a6 = __half2float(*(const __half*)(fb + (unsigned)(e6 & ~127)));
        float a7 = __half2float(*(const __half*)(fb + (unsigned)(e7 & ~127)));
        atomicAdd(&acc[((e0 & 31) << 6) + l], (int)(a0 * WSCALE));
        atomicAdd(&acc[((e1 & 31) << 6) + l], (int)(a1 * WSCALE));
        atomicAdd(&acc[((e2 & 31) << 6) + l], (int)(a2 * WSCALE));
        atomicAdd(&acc[((e3 & 31) << 6) + l], (int)(a3 * WSCALE));
        atomicAdd(&acc[((e4 & 31) << 6) + l], (int)(a4v * WSCALE));
        atomicAdd(&acc[((e5 & 31) << 6) + l], (int)(a5 * WSCALE));
        atomicAdd(&acc[((e6 & 31) << 6) + l], (int)(a6 * WSCALE));
        atomicAdd(&acc[((e7 & 31) << 6) + l], (int)(a7 * WSCALE));
    }
    __syncthreads();
    for (int n = wv; n < BNODES; n += 4) {
        int node = node0 + n;
        if (node >= NN) break;
        float di = dinv[node];
        float selfv = __half2float(feat[(size_t)node * HID + l]);
        float vv = ((float)acc[(n << 6) + l] * WINV + selfv) * di;
        if (MODE == 0) {
            vv += b1[l];
            vv = vv > 0.f ? vv : 0.f;
            unsigned long long mb = maskbits[node];
            vv = ((mb >> l) & 1ull) ? vv * 2.0f * di : 0.0f;
        }
        outp[(size_t)node * HID + l] = __float2half(vv);
    }
}

// ---- H. out = aggh @ W2 + b2 (fp32) via MFMA ----
__global__ __launch_bounds__(256) void k_mgemm2(const __half* __restrict__ aggh,
                                                const _Float16* __restrict__ w2f,
                                                const float* __restrict__ b2,
                                                float* __restrict__ out) {
    int wid = (blockIdx.x * 256 + threadIdx.x) >> 6;
    int l = threadIdx.x & 63;
    if (wid >= NN / 16) return;
    half8 bf[2][3];
    #pragma unroll
    for (int kk = 0; kk < 2; ++kk)
        #pragma unroll
        for (int n = 0; n < 3; ++n)
            bf[kk][n] = ((const half8*)w2f)[(kk * 3 + n) * 64 + l];
    f32x4 acc[3] = {};
    int arow = wid * 16 + (l & 15);
    const _Float16* hp = (const _Float16*)aggh + (size_t)arow * HID + (l >> 4) * 8;
    #pragma unroll
    for (int kk = 0; kk < 2; ++kk) {
        half8 af = *(const half8*)(hp + kk * 32);
        #pragma unroll
        for (int n = 0; n < 3; ++n)
            acc[n] = __builtin_amdgcn_mfma_f32_16x16x32_f16(af, bf[kk][n], acc[n], 0, 0, 0);
    }
    int orow = wid * 16 + (l >> 4) * 4;
    int ocol = l & 15;
    #pragma unroll
    for (int n = 0; n < 3; ++n) {
        int col = n * 16 + ocol;
        if (col < OUTD) {
            float bb = b2[col];
            #pragma unroll
            for (int r = 0; r < 4; ++r)
                out[(size_t)(orow + r) * OUTD + col] = acc[n][r] + bb;
        }
    }
}

extern "C" void kernel_launch(void* const* d_in, const int* in_sizes, int n_in,
                              void* d_out, int out_size, void* d_ws, size_t ws_size,
                              hipStream_t stream) {
    const float* x    = (const float*)d_in[0];
    const int*   ei   = (const int*)d_in[1];
    const int*   src  = ei;
    const int*   dst  = ei + NE;
    const float* W1   = (const float*)d_in[2];
    const float* b1   = (const float*)d_in[3];
    const float* W2   = (const float*)d_in[4];
    const float* b2   = (const float*)d_in[5];
    const float* mask = (const float*)d_in[6];
    float* out = (float*)d_out;

    char* ws = (char*)d_ws;
    int*      bfill  = (int*)ws;           ws += (size_t)NSB * 4;
    int*      sb_beg = (int*)ws;           ws += (size_t)NBAGG * 4;
    int*      sb_cnt = (int*)ws;           ws += (size_t)NBAGG * 4;
    float*    dinv   = (float*)ws;         ws += (size_t)NN * 4;
    unsigned long long* maskb = (unsigned long long*)ws; ws += (size_t)NN * 8;
    _Float16* w1f    = (_Float16*)ws;      ws += 16 * 64 * 8 * 2;
    _Float16* w2f    = (_Float16*)ws;      ws += 6 * 64 * 8 * 2;
    int*      csr    = (int*)ws;           ws += (size_t)NSB * CAP * 4;       // 8.0 MB
    __half*   h1s    = (__half*)ws;        ws += (size_t)(NN + 1) * HID * 2;  // 12.8 MB
    __half*   hhs    = (__half*)ws;        ws += (size_t)(NN + 1) * HID * 2;  // 12.8 MB
    int*      pairs  = (int*)hhs;          // alias: pairs (8 MB) dead before hhs written
    __half*   aggh   = h1s;                // alias: h1s dead after k_bagg<0>

    hipMemsetAsync(bfill, 0, (size_t)NSB * 4, stream);

    k_pairs   <<<(NE + CCHUNK - 1) / CCHUNK, 256, 0, stream>>>(src, dst, bfill, pairs);
    k_degdinv <<<NSB, 256, 0, stream>>>(pairs, bfill, dinv);
    k_csr     <<<NSB, 256, 0, stream>>>(pairs, bfill, sb_beg, sb_cnt, csr);
    k_maskbits<<<(NN + 3) / 4, 256, 0, stream>>>(mask, maskb);
    k_wprep   <<<1, 256, 0, stream>>>(W1, W2, w1f, w2f, h1s, hhs);

    k_mgemm1  <<<(NN / 16 + 3) / 4, 256, 0, stream>>>(x, w1f, dinv, h1s);
    k_bagg<0> <<<NBAGG, 256, 0, stream>>>(csr, sb_beg, sb_cnt, dinv, h1s, b1, maskb, hhs);
    k_bagg<1> <<<NBAGG, 256, 0, stream>>>(csr, sb_beg, sb_cnt, dinv, hhs, nullptr, nullptr, aggh);
    k_mgemm2  <<<(NN / 16 + 3) / 4, 256, 0, stream>>>(aggh, w2f, b2, out);
}

// Round 14
// 180.768 us; speedup vs baseline: 7.2588x; 1.0040x over previous
//
#include <hip/hip_runtime.h>
#include <hip/hip_fp16.h>

#define NN     100000
#define NE     1600000
#define FEAT   128
#define HID    64
#define OUTD   40
#define BNODES 32                         // aggregation bucket = 32 dst nodes
#define NSB    ((NN + 255) / 256)         // 391 superbuckets of 256 nodes
#define NBAGG  (NSB * 8)                  // 3128 aggregation buckets
#define CAP    5120                       // superbucket capacity (mean 4096, sd ~64)
#define CCHUNK 2048                       // edges per block in pair-scatter
#define WSCALE 262144.0f                  // 2^18 fixed-point scale
#define WINV   (1.0f / 262144.0f)

typedef _Float16 half8 __attribute__((ext_vector_type(8)));
typedef float    f32x4 __attribute__((ext_vector_type(4)));

// ---- A. scatter packed ex=(src<<8|dl) into superbucket segments ----
__global__ __launch_bounds__(256) void k_pairs(const int* __restrict__ src,
                                               const int* __restrict__ dst,
                                               int* __restrict__ bfill,
                                               int* __restrict__ pairs) {
    __shared__ int bcnt[NSB];
    __shared__ int gb[NSB];
    int t = threadIdx.x;
    for (int i = t; i < NSB; i += 256) bcnt[i] = 0;
    __syncthreads();
    int e0 = blockIdx.x * CCHUNK;
    int pk[8], bb[8], off[8];
    #pragma unroll
    for (int i = 0; i < 8; ++i) {
        int e = e0 + i * 256 + t;
        if (e < NE) {
            int d = dst[e];
            pk[i]  = (src[e] << 8) | (d & 255);
            bb[i]  = d >> 8;
            off[i] = atomicAdd(&bcnt[bb[i]], 1);
        } else bb[i] = -1;
    }
    __syncthreads();
    for (int i = t; i < NSB; i += 256) {
        int c = bcnt[i];
        gb[i] = c ? (i * CAP + atomicAdd(&bfill[i], c)) : 0;
    }
    __syncthreads();
    #pragma unroll
    for (int i = 0; i < 8; ++i)
        if (bb[i] >= 0) pairs[gb[bb[i]] + off[i]] = pk[i];
}

// ---- B. per-superbucket counting sort by (subbucket, src-stripe) + per-node dinv ----
__global__ __launch_bounds__(256) void k_csr(const int* __restrict__ pairs,
                                             const int* __restrict__ bfill,
                                             int* __restrict__ sb_beg,
                                             int* __restrict__ sb_cnt,
                                             int* __restrict__ csr,
                                             float* __restrict__ dinv) {
    __shared__ int hist[2048];
    __shared__ int exs[2048];
    __shared__ int nd[256];
    __shared__ int part[256];
    __shared__ int poff[9];
    __shared__ int sstart[8];
    __shared__ int dtot[8];
    int b = blockIdx.x, t = threadIdx.x;
    #pragma unroll
    for (int k = 0; k < 8; ++k) hist[t * 8 + k] = 0;
    nd[t] = 0;
    __syncthreads();
    int base = b * CAP, count = bfill[b];
    for (int i = t; i < count; i += 256) {
        int p = pairs[base + i];
        int key = (((p & 255) >> 5) << 8) | ((p >> 17) & 255);
        atomicAdd(&hist[key], 1);
        atomicAdd(&nd[p & 255], 1);
    }
    __syncthreads();
    {
        int node = (b << 8) + t;
        if (node < NN) dinv[node] = rsqrtf((float)nd[t] + 1.0f);
    }
    int loc[8], s0 = 0;
    #pragma unroll
    for (int k = 0; k < 8; ++k) { loc[k] = s0; s0 += hist[t * 8 + k]; }
    part[t] = s0;
    __syncthreads();
    for (int off = 1; off < 256; off <<= 1) {
        int u = (t >= off) ? part[t - off] : 0;
        __syncthreads();
        part[t] += u;
        __syncthreads();
    }
    int pex = part[t] - s0;
    #pragma unroll
    for (int k = 0; k < 8; ++k) exs[t * 8 + k] = pex + loc[k];
    __syncthreads();
    if (t < 8) {
        sstart[t] = exs[t * 256];
        int end = (t == 7) ? count : exs[(t + 1) * 256];
        dtot[t] = end - sstart[t];
    }
    __syncthreads();
    if (t == 0) {
        poff[0] = 0;
        for (int d = 0; d < 8; ++d) poff[d + 1] = poff[d] + ((dtot[d] + 31) & ~31);
    }
    __syncthreads();
    #pragma unroll
    for (int k = 0; k < 8; ++k) {
        int key = t * 8 + k;
        int d = key >> 8;
        exs[key] = poff[d] + (exs[key] - sstart[d]);
        hist[key] = 0;
    }
    __syncthreads();
    for (int i = t; i < count; i += 256) {
        int p = pairs[base + i];
        int key = (((p & 255) >> 5) << 8) | ((p >> 17) & 255);
        int pos = exs[key] + atomicAdd(&hist[key], 1);
        csr[base + pos] = ((p >> 8) << 7) | (p & 31);   // (src<<7)|dl5
    }
    for (int d = 0; d < 8; ++d) {
        int padded = (dtot[d] + 31) & ~31;
        for (int i = dtot[d] + t; i < padded; i += 256)
            csr[base + poff[d] + i] = (NN << 7);        // gathers zeroed row NN
    }
    if (t < 8) {
        sb_beg[b * 8 + t] = base + poff[t];
        sb_cnt[b * 8 + t] = (dtot[t] + 31) & ~31;
    }
}

// ---- C. compress dropout mask {0,2} -> 1 bit/elem ----
__global__ __launch_bounds__(256) void k_maskbits(const float* __restrict__ mask,
                                                  unsigned long long* __restrict__ mb) {
    int node = blockIdx.x * 4 + (threadIdx.x >> 6);
    if (node >= NN) return;
    int l = threadIdx.x & 63;
    float m = mask[(size_t)node * HID + l];
    unsigned long long bits = __ballot(m != 0.f);
    if (l == 0) mb[node] = bits;
}

// ---- D. pack W1/W2 into per-lane MFMA B-fragments (f16); zero pad rows NN ----
__global__ __launch_bounds__(256) void k_wprep(const float* __restrict__ W1,
                                               const float* __restrict__ W2,
                                               _Float16* __restrict__ w1f,
                                               _Float16* __restrict__ w2f,
                                               __half* __restrict__ h1s,
                                               __half* __restrict__ hhs) {
    int t = threadIdx.x;
    for (int it = t; it < 16 * 64; it += 256) {   // W1: kk 0..3 x n 0..3
        int f = it >> 6, l = it & 63;
        int kk = f >> 2, n = f & 3;
        int krow = kk * 32 + (l >> 4) * 8;
        int col  = n * 16 + (l & 15);
        #pragma unroll
        for (int i = 0; i < 8; ++i)
            w1f[it * 8 + i] = (_Float16)W1[(krow + i) * HID + col];
    }
    for (int it = t; it < 6 * 64; it += 256) {    // W2: kk 0..1 x n 0..2 (48-col pad)
        int f = it >> 6, l = it & 63;
        int kk = f / 3, n = f - kk * 3;
        int krow = kk * 32 + (l >> 4) * 8;
        int col  = n * 16 + (l & 15);
        #pragma unroll
        for (int i = 0; i < 8; ++i)
            w2f[it * 8 + i] = (col < OUTD) ? (_Float16)W2[(krow + i) * OUTD + col]
                                           : (_Float16)0.f;
    }
    if (t < HID) {                                 // zero the padding row NN
        h1s[(size_t)NN * HID + t] = __float2half(0.f);
        hhs[(size_t)NN * HID + t] = __float2half(0.f);
    }
}

// ---- E. h1s = f16((x @ W1) * dinv[row]) via MFMA ----
__global__ __launch_bounds__(256) void k_mgemm1(const float* __restrict__ x,
                                                const _Float16* __restrict__ w1f,
                                                const float* __restrict__ dinv,
                                                __half* __restrict__ h1s) {
    int wid = (blockIdx.x * 256 + threadIdx.x) >> 6;
    int l = threadIdx.x & 63;
    if (wid >= NN / 16) return;
    half8 bf[4][4];
    #pragma unroll
    for (int kk = 0; kk < 4; ++kk)
        #pragma unroll
        for (int n = 0; n < 4; ++n)
            bf[kk][n] = ((const half8*)w1f)[(kk * 4 + n) * 64 + l];
    f32x4 acc[4] = {};
    int arow = wid * 16 + (l & 15);
    const float* xp = x + (size_t)arow * FEAT + (l >> 4) * 8;
    #pragma unroll
    for (int kk = 0; kk < 4; ++kk) {
        float4 u0 = *(const float4*)(xp + kk * 32);
        float4 u1 = *(const float4*)(xp + kk * 32 + 4);
        half8 af;
        af[0] = (_Float16)u0.x; af[1] = (_Float16)u0.y;
        af[2] = (_Float16)u0.z; af[3] = (_Float16)u0.w;
        af[4] = (_Float16)u1.x; af[5] = (_Float16)u1.y;
        af[6] = (_Float16)u1.z; af[7] = (_Float16)u1.w;
        #pragma unroll
        for (int n = 0; n < 4; ++n)
            acc[n] = __builtin_amdgcn_mfma_f32_16x16x32_f16(af, bf[kk][n], acc[n], 0, 0, 0);
    }
    int orow = wid * 16 + (l >> 4) * 4;
    int ocol = l & 15;
    float dv[4];
    #pragma unroll
    for (int r = 0; r < 4; ++r) dv[r] = dinv[orow + r];
    #pragma unroll
    for (int n = 0; n < 4; ++n)
        #pragma unroll
        for (int r = 0; r < 4; ++r)
            h1s[(size_t)(orow + r) * HID + n * 16 + ocol] = __float2half(acc[n][r] * dv[r]);
}

// ---- F. block-per-subbucket edge sweep, LDS int accumulator (feats pre-scaled by dinv[src]).
// MODE 0: hhs = f16(relu((acc+self)*di + b1) * mask * di)
// MODE 1: out = ((acc+self)*di) @ W2 + b2  (MFMA fused in-block)
template<int MODE>
__global__ __launch_bounds__(256) void k_bagg(const int* __restrict__ csr,
                                              const int* __restrict__ sb_beg,
                                              const int* __restrict__ sb_cnt,
                                              const float* __restrict__ dinv,
                                              const __half* __restrict__ feat,
                                              const float* __restrict__ b1,
                                              const unsigned long long* __restrict__ maskbits,
                                              __half* __restrict__ outp,
                                              const _Float16* __restrict__ w2f,
                                              const float* __restrict__ b2,
                                              float* __restrict__ outf) {
    __shared__ int acc[BNODES * HID];     // 8 KB
    int t = threadIdx.x, wv = t >> 6, l = t & 63;
    int bb = blockIdx.x;
    int4* a4 = (int4*)acc;
    for (int i = t; i < BNODES * HID / 4; i += 256) a4[i] = make_int4(0, 0, 0, 0);
    __syncthreads();
    int base  = sb_beg[bb];
    int count = sb_cnt[bb];               // multiple of 32
    int node0 = (bb >> 3) * 256 + (bb & 7) * 32;
    const char* fb = (const char*)feat + ((size_t)l * 2);
    for (int j = wv * 16; j < count; j += 64) {
        int e[16];
        #pragma unroll
        for (int i = 0; i < 16; ++i) e[i] = csr[base + j + i];
        float a[16];
        #pragma unroll
        for (int i = 0; i < 16; ++i)
            a[i] = __half2float(*(const __half*)(fb + (unsigned)(e[i] & ~127)));
        #pragma unroll
        for (int i = 0; i < 16; ++i)
            atomicAdd(&acc[((e[i] & 31) << 6) + l], (int)(a[i] * WSCALE));
    }
    __syncthreads();
    if (MODE == 0) {
        for (int n = wv; n < BNODES; n += 4) {
            int node = node0 + n;
            if (node >= NN) break;
            float di = dinv[node];
            float selfv = __half2float(feat[(size_t)node * HID + l]);
            float vv = ((float)acc[(n << 6) + l] * WINV + selfv) * di;
            vv += b1[l];
            vv = vv > 0.f ? vv : 0.f;
            unsigned long long mb = maskbits[node];
            vv = ((mb >> l) & 1ull) ? vv * 2.0f * di : 0.0f;
            outp[(size_t)node * HID + l] = __float2half(vv);
        }
    } else {
        if (wv < 2) {                     // 2 waves x 16 rows = 32 nodes
            half8 bf[2][3];
            #pragma unroll
            for (int kk = 0; kk < 2; ++kk)
                #pragma unroll
                for (int n = 0; n < 3; ++n)
                    bf[kk][n] = ((const half8*)w2f)[(kk * 3 + n) * 64 + l];
            int lrow = wv * 16 + (l & 15);
            int node = node0 + lrow;
            int srow = node < NN ? node : NN;          // row NN is zeroed
            float di = dinv[node < NN ? node : NN - 1];
            int k0 = (l >> 4) * 8;
            half8 af[2];
            #pragma unroll
            for (int kk = 0; kk < 2; ++kk)
                #pragma unroll
                for (int i = 0; i < 8; ++i) {
                    int k = kk * 32 + k0 + i;
                    float v = ((float)acc[(lrow << 6) + k] * WINV
                              + __half2float(feat[(size_t)srow * HID + k])) * di;
                    af[kk][i] = (_Float16)v;
                }
            f32x4 o[3] = {};
            #pragma unroll
            for (int kk = 0; kk < 2; ++kk)
                #pragma unroll
                for (int n = 0; n < 3; ++n)
                    o[n] = __builtin_amdgcn_mfma_f32_16x16x32_f16(af[kk], bf[kk][n], o[n], 0, 0, 0);
            int orow = node0 + wv * 16 + (l >> 4) * 4;
            int ocol = l & 15;
            #pragma unroll
            for (int n = 0; n < 3; ++n) {
                int col = n * 16 + ocol;
                if (col < OUTD) {
                    float bbias = b2[col];
                    #pragma unroll
                    for (int r = 0; r < 4; ++r) {
                        int row = orow + r;
                        if (row < NN)
                            outf[(size_t)row * OUTD + col] = o[n][r] + bbias;
                    }
                }
            }
        }
    }
}

extern "C" void kernel_launch(void* const* d_in, const int* in_sizes, int n_in,
                              void* d_out, int out_size, void* d_ws, size_t ws_size,
                              hipStream_t stream) {
    const float* x    = (const float*)d_in[0];
    const int*   ei   = (const int*)d_in[1];
    const int*   src  = ei;
    const int*   dst  = ei + NE;
    const float* W1   = (const float*)d_in[2];
    const float* b1   = (const float*)d_in[3];
    const float* W2   = (const float*)d_in[4];
    const float* b2   = (const float*)d_in[5];
    const float* mask = (const float*)d_in[6];
    float* out = (float*)d_out;

    char* ws = (char*)d_ws;
    int*      bfill  = (int*)ws;           ws += (size_t)NSB * 4;
    int*      sb_beg = (int*)ws;           ws += (size_t)NBAGG * 4;
    int*      sb_cnt = (int*)ws;           ws += (size_t)NBAGG * 4;
    float*    dinv   = (float*)ws;         ws += (size_t)NN * 4;
    unsigned long long* maskb = (unsigned long long*)ws; ws += (size_t)NN * 8;
    _Float16* w1f    = (_Float16*)ws;      ws += 16 * 64 * 8 * 2;
    _Float16* w2f    = (_Float16*)ws;      ws += 6 * 64 * 8 * 2;
    int*      csr    = (int*)ws;           ws += (size_t)NSB * CAP * 4;       // 8.0 MB
    __half*   h1s    = (__half*)ws;        ws += (size_t)(NN + 1) * HID * 2;  // 12.8 MB
    __half*   hhs    = (__half*)ws;        ws += (size_t)(NN + 1) * HID * 2;  // 12.8 MB
    int*      pairs  = (int*)hhs;          // alias: pairs (8 MB) dead before hhs written

    hipMemsetAsync(bfill, 0, (size_t)NSB * 4, stream);

    k_pairs   <<<(NE + CCHUNK - 1) / CCHUNK, 256, 0, stream>>>(src, dst, bfill, pairs);
    k_csr     <<<NSB, 256, 0, stream>>>(pairs, bfill, sb_beg, sb_cnt, csr, dinv);
    k_maskbits<<<(NN + 3) / 4, 256, 0, stream>>>(mask, maskb);
    k_wprep   <<<1, 256, 0, stream>>>(W1, W2, w1f, w2f, h1s, hhs);

    k_mgemm1  <<<(NN / 16 + 3) / 4, 256, 0, stream>>>(x, w1f, dinv, h1s);
    k_bagg<0> <<<NBAGG, 256, 0, stream>>>(csr, sb_beg, sb_cnt, dinv, h1s, b1, maskb,
                                          hhs, nullptr, nullptr, nullptr);
    k_bagg<1> <<<NBAGG, 256, 0, stream>>>(csr, sb_beg, sb_cnt, dinv, hhs, nullptr, nullptr,
                                          nullptr, w2f, b2, out);
}